// Round 3
// baseline (739.388 us; speedup 1.0000x reference)
//
#include <hip/hip_runtime.h>
#include <hip/hip_bf16.h>

// Problem constants (GroupGMM): B=8192, I=512, G=32, C=16, D=32, CD=512
#define BATCH 8192
#define IDIM  512
#define GDIM  32
#define NOUT  1040   // 16 (pi) + 512 (mu) + 512 (sigma)
#define NPAD  1152   // 9 * 128 tiles
#define KTOT  16416  // G*I + G bias rows
#define BK    32
#define NSPLIT 4
#define KITERS 513   // KTOT/BK
#define APAD  40     // A-tile LDS row stride in shorts (32+8 pad -> conflict-free)
#define BPAD  40     // B-tile LDS row stride (reg staging frees us from DMA layout)

typedef short bf16x8 __attribute__((ext_vector_type(8)));   // 8 bf16 (4 VGPRs)
typedef float floatx4 __attribute__((ext_vector_type(4)));  // MFMA acc

__device__ inline unsigned pk2(float a, float b) {
    union { __hip_bfloat162 h2; unsigned u; } cv;
    cv.h2 = __float22bfloat162_rn(float2{a, b});
    return cv.u;
}

// ---------------- prep: Wt[n][k] bf16, n-major, bias folded as k in [16384,16416) ----
__global__ void prep_wt(const float* __restrict__ Wmu, const float* __restrict__ bmu,
                        const float* __restrict__ Wsig, const float* __restrict__ bsig,
                        const float* __restrict__ Wpi, const float* __restrict__ bpi,
                        unsigned short* __restrict__ Wt) {
    int n = blockIdx.y * 256 + threadIdx.x;
    if (n >= NPAD) return;
    int k0 = blockIdx.x * 8;
    float v[8];
#pragma unroll
    for (int j = 0; j < 8; ++j) {
        int k = k0 + j;
        float val = 0.0f;
        if (n < NOUT) {
            if (k < GDIM * IDIM) {
                int gg = k >> 9, i = k & 511;
                if (n < 16)        val = Wpi [(gg * 512 + i) * 16  + n];
                else if (n < 528)  val = Wmu [(gg * 512 + i) * 512 + (n - 16)];
                else               val = Wsig[(gg * 512 + i) * 512 + (n - 528)];
            } else {
                int gg = k - GDIM * IDIM;
                if (n < 16)        val = bpi [gg * 16  + n];
                else if (n < 528)  val = bmu [gg * 512 + (n - 16)];
                else               val = bsig[gg * 512 + (n - 528)];
            }
        }
        v[j] = val;
    }
    uint4 p;
    p.x = pk2(v[0], v[1]); p.y = pk2(v[2], v[3]);
    p.z = pk2(v[4], v[5]); p.w = pk2(v[6], v[7]);
    *(uint4*)&Wt[(size_t)n * KTOT + k0] = p;
}

// ---------------- GEMM (split-K, reg-pipelined): acc += A[b,kr] @ Wt[kr,n] ---------
// A generated on the fly: A[b, g*512+i] = x[b,i]*g[b,g]; A[b,16384+j] = g[b,j].
// Pipeline: stage(cur regs) | barrier | issue loads(it+1) | ds_read+MFMA | barrier.
// Global loads land in VGPRs, so their waitcnt sits at next iter's cvt (covered by
// a full MFMA block), not at the barrier like global_load_lds forces.
__global__ __launch_bounds__(256) void gemm_gmm(
        const float* __restrict__ x, const float* __restrict__ g,
        const unsigned short* __restrict__ Wt, float* __restrict__ accbuf) {
    __shared__ __align__(16) unsigned short lds_a[128 * APAD];  // 10 KB
    __shared__ __align__(16) unsigned short lds_b[128 * BPAD];  // 10 KB

    const int t    = threadIdx.x;
    const int lane = t & 63;
    const int w    = t >> 6;
    const int wm   = (w & 1) * 64;
    const int wn   = (w >> 1) * 64;
    const int q    = lane >> 4;
    const int l15  = lane & 15;

    const int m0 = blockIdx.x * 128;
    const int n0 = blockIdx.y * 128;
    const int z  = blockIdx.z;
    const int it0 = (KITERS * z) / NSPLIT;
    const int it1 = (KITERS * (z + 1)) / NSPLIT;

    floatx4 acc[4][4] = {};

    // A staging: thread t handles row (t>>1), 16 k-elems at half (t&1)
    const int arow  = t >> 1;
    const int ahalf = t & 1;
    const float* xrow = x + (size_t)(m0 + arow) * IDIM + ahalf * 16;
    const float* grow = g + (size_t)(m0 + arow) * GDIM;
    unsigned short* ldsA0 = lds_a + arow * APAD + ahalf * 16;

    // B staging via regs: thread t covers rows (t>>2) and 64+(t>>2), chunk (t&3)
    const int brow = t >> 2;
    const int bc   = t & 3;
    const unsigned short* WtB0 = Wt + (size_t)(n0 + brow) * KTOT + bc * 8;
    const unsigned short* WtB1 = Wt + (size_t)(n0 + 64 + brow) * KTOT + bc * 8;
    unsigned short* ldsB0 = lds_b + brow * BPAD + bc * 8;
    unsigned short* ldsB1 = lds_b + (64 + brow) * BPAD + bc * 8;

    uint4 rb0, rb1;
    float4 rx0, rx1, rx2, rx3;
    float sc;

    auto issue = [&](int it) {
        const int k0 = it * BK;
        rb0 = *(const uint4*)(WtB0 + k0);
        rb1 = *(const uint4*)(WtB1 + k0);
        const float4* src;
        if (k0 < GDIM * IDIM) {
            src = (const float4*)(xrow + (k0 & 511));
            sc  = grow[k0 >> 9];
        } else {                      // bias rows: A[b, 16384+j] = g[b, j]
            src = (const float4*)(grow + ahalf * 16);
            sc  = 1.0f;
        }
        rx0 = src[0]; rx1 = src[1]; rx2 = src[2]; rx3 = src[3];
    };

    issue(it0);
    for (int it = it0; it < it1; ++it) {
        // ---- stage current tile from regs (cvt waits on loads issued last iter) ----
        uint4 pa, pb;
        pa.x = pk2(rx0.x * sc, rx0.y * sc); pa.y = pk2(rx0.z * sc, rx0.w * sc);
        pa.z = pk2(rx1.x * sc, rx1.y * sc); pa.w = pk2(rx1.z * sc, rx1.w * sc);
        pb.x = pk2(rx2.x * sc, rx2.y * sc); pb.y = pk2(rx2.z * sc, rx2.w * sc);
        pb.z = pk2(rx3.x * sc, rx3.y * sc); pb.w = pk2(rx3.z * sc, rx3.w * sc);
        *(uint4*)ldsA0       = pa;
        *(uint4*)(ldsA0 + 8) = pb;
        *(uint4*)ldsB0 = rb0;
        *(uint4*)ldsB1 = rb1;
        __syncthreads();
        // ---- issue next iteration's global loads (covered by MFMA block below) ----
        issue(it + 1 < it1 ? it + 1 : it);   // last iter: harmless reload
        // ---- fragments + MFMA ----
        bf16x8 af[4], bfr[4];
#pragma unroll
        for (int tm = 0; tm < 4; ++tm)
            af[tm] = *(const bf16x8*)&lds_a[(wm + tm * 16 + l15) * APAD + q * 8];
#pragma unroll
        for (int tn = 0; tn < 4; ++tn)
            bfr[tn] = *(const bf16x8*)&lds_b[(wn + tn * 16 + l15) * BPAD + q * 8];
#pragma unroll
        for (int tm = 0; tm < 4; ++tm)
#pragma unroll
            for (int tn = 0; tn < 4; ++tn)
                acc[tm][tn] = __builtin_amdgcn_mfma_f32_16x16x32_bf16(
                    af[tm], bfr[tn], acc[tm][tn], 0, 0, 0);
        __syncthreads();
    }

    // ---- epilogue: atomic-accumulate fp32 partials (softplus deferred) ----
#pragma unroll
    for (int tn = 0; tn < 4; ++tn) {
        int n = n0 + wn + tn * 16 + l15;
        if (n >= NOUT) continue;
#pragma unroll
        for (int tm = 0; tm < 4; ++tm) {
            int mbase = m0 + wm + tm * 16 + q * 4;
#pragma unroll
            for (int r = 0; r < 4; ++r)
                atomicAdd(&accbuf[(size_t)(mbase + r) * NOUT + n], acc[tm][tn][r]);
        }
    }
}

// ---------------- finalize: softplus on sigma region, copy to out ------------------
__global__ __launch_bounds__(256) void finalize(const float* __restrict__ accbuf,
                                                float* __restrict__ out) {
    size_t f = ((size_t)blockIdx.x * 256 + threadIdx.x) * 4;  // NOUT%4==0: same row
    int col = (int)(f % NOUT);
    float4 v = *(const float4*)(accbuf + f);
    float r[4] = {v.x, v.y, v.z, v.w};
#pragma unroll
    for (int j = 0; j < 4; ++j) {
        if (col + j >= 528) {
            float vv = r[j];
            float sp = (vv > 15.0f) ? vv : log1pf(expf(vv));
            r[j] = sp + 1e-7f;
        }
    }
    *(float4*)(out + f) = make_float4(r[0], r[1], r[2], r[3]);
}

extern "C" void kernel_launch(void* const* d_in, const int* in_sizes, int n_in,
                              void* d_out, int out_size, void* d_ws, size_t ws_size,
                              hipStream_t stream) {
    const float* x    = (const float*)d_in[0];
    const float* g    = (const float*)d_in[1];
    const float* Wmu  = (const float*)d_in[2];
    const float* bmu  = (const float*)d_in[3];
    const float* Wsig = (const float*)d_in[4];
    const float* bsig = (const float*)d_in[5];
    const float* Wpi  = (const float*)d_in[6];
    const float* bpi  = (const float*)d_in[7];
    float* out = (float*)d_out;

    unsigned short* Wt = (unsigned short*)d_ws;          // NPAD*KTOT*2 = 37.82 MB
    float* accbuf = (float*)((char*)d_ws + (size_t)NPAD * KTOT * 2);  // B*NOUT*4 = 34.08 MB

    hipMemsetAsync(accbuf, 0, (size_t)BATCH * NOUT * sizeof(float), stream);
    prep_wt<<<dim3(KTOT / 8, 5), 256, 0, stream>>>(Wmu, bmu, Wsig, bsig, Wpi, bpi, Wt);
    gemm_gmm<<<dim3(BATCH / 128, NPAD / 128, NSPLIT), 256, 0, stream>>>(x, g, Wt, accbuf);
    finalize<<<(BATCH * NOUT / 4 + 255) / 256, 256, 0, stream>>>(accbuf, out);
}

// Round 4
// 616.556 us; speedup vs baseline: 1.1992x; 1.1992x over previous
//
#include <hip/hip_runtime.h>
#include <hip/hip_bf16.h>

// GroupGMM: B=8192, I=512, G=32, C=16, D=32; out = concat(pi[16], mu[512], softplus(sig)[512])
#define BATCH 8192
#define IDIM  512
#define GDIM  32
#define NOUT  1040
#define NPAD  1152     // 9 * 128 n-tiles
#define KW    16384    // G*I
#define GPERZ 16       // groups per z-slice (NSPLIT=2)
#define CHUNK 64       // k elems per chunk
#define CPG   8        // chunks per group (512/64)

typedef short bf16x8 __attribute__((ext_vector_type(8)));   // 8 bf16 (4 VGPRs)
typedef float floatx4 __attribute__((ext_vector_type(4)));  // MFMA acc

#define GLP(p)  (const __attribute__((address_space(1))) void*)(p)
#define LDSP(p) (__attribute__((address_space(3))) void*)(p)

__device__ inline unsigned pk2(float a, float b) {
    union { __hip_bfloat162 h2; unsigned u; } cv;
    cv.h2 = __float22bfloat162_rn(float2{a, b});
    return cv.u;
}

// ---- cvt fp32 -> bf16, 8 elems/thread (used for xb and gb) ------------------------
__global__ void cvt_bf16(const float* __restrict__ s, unsigned short* __restrict__ d) {
    int t = blockIdx.x * 256 + threadIdx.x;
    const float4* sp = (const float4*)s + (size_t)t * 2;
    float4 a = sp[0], b = sp[1];
    uint4 p;
    p.x = pk2(a.x, a.y); p.y = pk2(a.z, a.w);
    p.z = pk2(b.x, b.y); p.w = pk2(b.z, b.w);
    *(uint4*)(d + (size_t)t * 8) = p;
}

// ---- prep: Wt[n][16384] bf16 (weights only; zero-padded rows n>=1040) -------------
__global__ void prep_wt(const float* __restrict__ Wmu, const float* __restrict__ Wsig,
                        const float* __restrict__ Wpi, unsigned short* __restrict__ Wt) {
    int n = blockIdx.y * 256 + threadIdx.x;
    if (n >= NPAD) return;
    int k0 = blockIdx.x * 8;
    float v[8];
#pragma unroll
    for (int j = 0; j < 8; ++j) {
        int k = k0 + j, gg = k >> 9, i = k & 511;
        float val = 0.0f;
        if (n < 16)         val = Wpi [(gg * 512 + i) * 16  + n];
        else if (n < 528)   val = Wmu [(gg * 512 + i) * 512 + (n - 16)];
        else if (n < NOUT)  val = Wsig[(gg * 512 + i) * 512 + (n - 528)];
        v[j] = val;
    }
    uint4 p;
    p.x = pk2(v[0], v[1]); p.y = pk2(v[2], v[3]);
    p.z = pk2(v[4], v[5]); p.w = pk2(v[6], v[7]);
    *(uint4*)&Wt[(size_t)n * KW + k0] = p;
}

// ---- prep: Wb[n][32] bf16 = concatenated biases, n-major --------------------------
__global__ void prep_wb(const float* __restrict__ bmu, const float* __restrict__ bsig,
                        const float* __restrict__ bpi, unsigned short* __restrict__ Wb) {
    int n = blockIdx.y * 256 + threadIdx.x;
    if (n >= NPAD) return;
    int k0 = blockIdx.x * 8;
    float v[8];
#pragma unroll
    for (int j = 0; j < 8; ++j) {
        int gg = k0 + j;
        float val = 0.0f;
        if (n < 16)         val = bpi [gg * 16  + n];
        else if (n < 528)   val = bmu [gg * 512 + (n - 16)];
        else if (n < NOUT)  val = bsig[gg * 512 + (n - 528)];
        v[j] = val;
    }
    uint4 p;
    p.x = pk2(v[0], v[1]); p.y = pk2(v[2], v[3]);
    p.z = pk2(v[4], v[5]); p.w = pk2(v[6], v[7]);
    *(uint4*)&Wb[(size_t)n * GDIM + k0] = p;
}

// ---- GEMM: group-partial accumulation, all-DMA staging, 1 barrier/chunk -----------
// acc[m,n] = sum_gg g[m,gg] * (xb[m,:] @ Wt_gg[:,n])  (+ bias via 17th mini-group, z=0)
__global__ __launch_bounds__(256) void gemm_gmm(
        const unsigned short* __restrict__ xb, const unsigned short* __restrict__ gb,
        const float* __restrict__ g, const unsigned short* __restrict__ Wt,
        const unsigned short* __restrict__ Wb, float* __restrict__ accbuf) {
    __shared__ unsigned short lA[2][128 * CHUNK];  // 2 x 16 KB, XOR-swizzled
    __shared__ unsigned short lB[2][128 * CHUNK];  // 2 x 16 KB
    __shared__ float gsc[GPERZ * 128];             // scales g[m0+row][zg+gg], [gg][row]

    const int t = threadIdx.x, lane = t & 63, w = t >> 6;
    const int wm = (w & 1) * 64, wn = (w >> 1) * 64;
    const int q = lane >> 4, l15 = lane & 15;
    const int m0 = blockIdx.x * 128, n0 = blockIdx.y * 128, z = blockIdx.z;
    const int zg = z * GPERZ;

    // stage scales: gsc[gg*128+row] = g[m0+row][zg+gg] (first read after 8+ barriers)
#pragma unroll
    for (int j = 0; j < 8; ++j) {
        int slot = t + 256 * j;
        int gg = slot >> 7, row = slot & 127;
        gsc[slot] = g[(size_t)(m0 + row) * GDIM + zg + gg];
    }

    // DMA source bases. Dest slot s = t+256j holds (row=s>>3, seg=(s&7)^((s>>3)&7)),
    // so LDS slot(row,seg) = row*8 + (seg^(row&7)) -- self-inverse swizzle.
    const int rowS = t >> 3, segS = (t & 7) ^ ((t >> 3) & 7);
    const unsigned short* aSrc = xb + (size_t)(m0 + rowS) * IDIM + segS * 8;
    const unsigned short* bSrc = Wt + (size_t)(n0 + rowS) * KW + (size_t)zg * IDIM + segS * 8;

    // read-side byte offsets (row&7 == l15&7 since wm,tm*16 are mult of 8/16)
    const int xa = l15 & 7;
    const int offA0 = ((wm + l15) * 8 + (q ^ xa)) * 16;        // kstep 0; +tm*2048
    const int offA1 = ((wm + l15) * 8 + ((4 + q) ^ xa)) * 16;  // kstep 1
    const int offB0 = ((wn + l15) * 8 + (q ^ xa)) * 16;
    const int offB1 = ((wn + l15) * 8 + ((4 + q) ^ xa)) * 16;

    floatx4 acc[4][4] = {};
    floatx4 P[4][4] = {};
    const int NC = GPERZ * CPG;  // 128 chunks

    // prologue: DMA chunk 0 -> buf 0
#pragma unroll
    for (int j = 0; j < 4; ++j) {
        __builtin_amdgcn_global_load_lds(GLP(aSrc + j * 32 * IDIM),
                                         LDSP(&lA[0][(t + 256 * j) * 8]), 16, 0, 0);
        __builtin_amdgcn_global_load_lds(GLP(bSrc + (size_t)j * 32 * KW),
                                         LDSP(&lB[0][(t + 256 * j) * 8]), 16, 0, 0);
    }

    for (int c = 0; c < NC; ++c) {
        __syncthreads();  // drains DMA for buf[c&1]; prev reads of other buf are done
        const int buf = c & 1;
        if (c + 1 < NC) {  // prefetch c+1 -> other buf; drained only at NEXT barrier
            const unsigned short* a = aSrc + ((c + 1) & 7) * CHUNK;
            const unsigned short* b = bSrc + (c + 1) * CHUNK;
#pragma unroll
            for (int j = 0; j < 4; ++j) {
                __builtin_amdgcn_global_load_lds(GLP(a + j * 32 * IDIM),
                                                 LDSP(&lA[buf ^ 1][(t + 256 * j) * 8]), 16, 0, 0);
                __builtin_amdgcn_global_load_lds(GLP(b + (size_t)j * 32 * KW),
                                                 LDSP(&lB[buf ^ 1][(t + 256 * j) * 8]), 16, 0, 0);
            }
        }
        const char* A  = (const char*)lA[buf];
        const char* Bp = (const char*)lB[buf];
        bf16x8 af[4], bfr[4];
        // kstep 0
#pragma unroll
        for (int tm = 0; tm < 4; ++tm) af[tm]  = *(const bf16x8*)(A  + offA0 + tm * 2048);
#pragma unroll
        for (int tn = 0; tn < 4; ++tn) bfr[tn] = *(const bf16x8*)(Bp + offB0 + tn * 2048);
#pragma unroll
        for (int tm = 0; tm < 4; ++tm)
#pragma unroll
            for (int tn = 0; tn < 4; ++tn)
                P[tm][tn] = __builtin_amdgcn_mfma_f32_16x16x32_bf16(af[tm], bfr[tn], P[tm][tn], 0, 0, 0);
        // kstep 1
#pragma unroll
        for (int tm = 0; tm < 4; ++tm) af[tm]  = *(const bf16x8*)(A  + offA1 + tm * 2048);
#pragma unroll
        for (int tn = 0; tn < 4; ++tn) bfr[tn] = *(const bf16x8*)(Bp + offB1 + tn * 2048);
#pragma unroll
        for (int tm = 0; tm < 4; ++tm)
#pragma unroll
            for (int tn = 0; tn < 4; ++tn)
                P[tm][tn] = __builtin_amdgcn_mfma_f32_16x16x32_bf16(af[tm], bfr[tn], P[tm][tn], 0, 0, 0);
        // group boundary: acc += g[m,gg] * P; rezero P
        if ((c & 7) == 7) {
            const int gg = c >> 3;
#pragma unroll
            for (int tm = 0; tm < 4; ++tm) {
                floatx4 s4 = *(const floatx4*)&gsc[gg * 128 + wm + tm * 16 + q * 4];
#pragma unroll
                for (int tn = 0; tn < 4; ++tn) {
#pragma unroll
                    for (int r = 0; r < 4; ++r)
                        acc[tm][tn][r] += s4[r] * P[tm][tn][r];
                    P[tm][tn] = (floatx4){0.f, 0.f, 0.f, 0.f};
                }
            }
        }
    }

    // ---- bias mini-group (z==0): acc += bf16(g) @ Wb, K=32 -----------------------
    if (z == 0) {
        __syncthreads();
        const int rowC = t >> 2, segC = (t & 3) ^ ((t >> 3) & 3);
        const unsigned short* ga = gb + (size_t)(m0 + rowC) * GDIM + segC * 8;
        const unsigned short* wb = Wb + (size_t)(n0 + rowC) * GDIM + segC * 8;
#pragma unroll
        for (int j = 0; j < 2; ++j) {
            __builtin_amdgcn_global_load_lds(GLP(ga + j * 64 * GDIM),
                                             LDSP(&lA[0][(t + 256 * j) * 8]), 16, 0, 0);
            __builtin_amdgcn_global_load_lds(GLP(wb + j * 64 * GDIM),
                                             LDSP(&lB[0][(t + 256 * j) * 8]), 16, 0, 0);
        }
        __syncthreads();
        const int xc = (l15 >> 1) & 3;  // slot(row,seg)=row*4+(seg^((row>>1)&3))
        const int offCA = ((wm + l15) * 4 + (q ^ xc)) * 16;  // +tm*1024
        const int offCB = ((wn + l15) * 4 + (q ^ xc)) * 16;
        bf16x8 af[4], bfr[4];
#pragma unroll
        for (int tm = 0; tm < 4; ++tm) af[tm]  = *(const bf16x8*)((const char*)lA[0] + offCA + tm * 1024);
#pragma unroll
        for (int tn = 0; tn < 4; ++tn) bfr[tn] = *(const bf16x8*)((const char*)lB[0] + offCB + tn * 1024);
#pragma unroll
        for (int tm = 0; tm < 4; ++tm)
#pragma unroll
            for (int tn = 0; tn < 4; ++tn) {
                P[tm][tn] = __builtin_amdgcn_mfma_f32_16x16x32_bf16(af[tm], bfr[tn], P[tm][tn], 0, 0, 0);
#pragma unroll
                for (int r = 0; r < 4; ++r) acc[tm][tn][r] += P[tm][tn][r];
            }
    }

    // ---- epilogue: atomic-accumulate fp32 partials -------------------------------
#pragma unroll
    for (int tn = 0; tn < 4; ++tn) {
        int n = n0 + wn + tn * 16 + l15;
        if (n >= NOUT) continue;
#pragma unroll
        for (int tm = 0; tm < 4; ++tm) {
            int mbase = m0 + wm + tm * 16 + q * 4;
#pragma unroll
            for (int r = 0; r < 4; ++r)
                atomicAdd(&accbuf[(size_t)(mbase + r) * NOUT + n], acc[tm][tn][r]);
        }
    }
}

// ---- finalize: softplus on sigma region, copy to out ------------------------------
__global__ __launch_bounds__(256) void finalize(const float* __restrict__ accbuf,
                                                float* __restrict__ out) {
    size_t f = ((size_t)blockIdx.x * 256 + threadIdx.x) * 4;  // NOUT%4==0: same row
    int col = (int)(f % NOUT);
    float4 v = *(const float4*)(accbuf + f);
    float r[4] = {v.x, v.y, v.z, v.w};
#pragma unroll
    for (int j = 0; j < 4; ++j) {
        if (col + j >= 528) {
            float vv = r[j];
            float sp = (vv > 15.0f) ? vv : log1pf(expf(vv));
            r[j] = sp + 1e-7f;
        }
    }
    *(float4*)(out + f) = make_float4(r[0], r[1], r[2], r[3]);
}

extern "C" void kernel_launch(void* const* d_in, const int* in_sizes, int n_in,
                              void* d_out, int out_size, void* d_ws, size_t ws_size,
                              hipStream_t stream) {
    const float* x    = (const float*)d_in[0];
    const float* g    = (const float*)d_in[1];
    const float* Wmu  = (const float*)d_in[2];
    const float* bmu  = (const float*)d_in[3];
    const float* Wsig = (const float*)d_in[4];
    const float* bsig = (const float*)d_in[5];
    const float* Wpi  = (const float*)d_in[6];
    const float* bpi  = (const float*)d_in[7];
    float* out = (float*)d_out;

    // workspace layout (~80.8 MB total)
    char* ws = (char*)d_ws;
    unsigned short* Wt = (unsigned short*)ws;                    ws += (size_t)NPAD * KW * 2;    // 37.75 MB
    unsigned short* xb = (unsigned short*)ws;                    ws += (size_t)BATCH * IDIM * 2; //  8.0 MB
    unsigned short* gb = (unsigned short*)ws;                    ws += (size_t)BATCH * GDIM * 2; //  0.5 MB
    unsigned short* Wb = (unsigned short*)ws;                    ws += (size_t)NPAD * GDIM * 2;  //  0.07 MB
    float* accbuf = (float*)ws;                                                                 // 34.08 MB

    cvt_bf16<<<BATCH * IDIM / 2048, 256, 0, stream>>>(x, xb);    // 2048 blocks
    cvt_bf16<<<BATCH * GDIM / 2048, 256, 0, stream>>>(g, gb);    // 128 blocks
    prep_wt<<<dim3(KW / 8, 5), 256, 0, stream>>>(Wmu, Wsig, Wpi, Wt);
    prep_wb<<<dim3(GDIM / 8, 5), 256, 0, stream>>>(bmu, bsig, bpi, Wb);
    hipMemsetAsync(accbuf, 0, (size_t)BATCH * NOUT * sizeof(float), stream);
    gemm_gmm<<<dim3(BATCH / 128, NPAD / 128, 2), 256, 0, stream>>>(xb, gb, g, Wt, Wb, accbuf);
    finalize<<<BATCH * NOUT / 1024, 256, 0, stream>>>(accbuf, out);
}